// Round 9
// baseline (195.630 us; speedup 1.0000x reference)
//
#include <hip/hip_runtime.h>
#include <math.h>
#include <stdint.h>

typedef _Float16 half8v __attribute__((ext_vector_type(8)));
typedef _Float16 half4v __attribute__((ext_vector_type(4)));
typedef _Float16 half2v __attribute__((ext_vector_type(2)));
typedef __fp16 fp16x2 __attribute__((ext_vector_type(2)));
typedef float floatx4 __attribute__((ext_vector_type(4)));

#define MFMA16(a, b, c) __builtin_amdgcn_mfma_f32_16x16x32_f16(a, b, c, 0, 0, 0)

// Q pre-scale: 1/sqrt(64) * log2(e), folded so attention uses exp2 directly.
#define QSCALE 0.18033688011112f

// Async global->LDS, 16B per lane. LDS dest must be wave-uniform base + lane*16;
// the GLOBAL source address is per-lane arbitrary (it's a gather).
__device__ __forceinline__ void gld_lds16(const void* g, void* l) {
  __builtin_amdgcn_global_load_lds(
      (const __attribute__((address_space(1))) uint32_t*)(uintptr_t)g,
      (__attribute__((address_space(3))) uint32_t*)(uintptr_t)l, 16, 0, 0);
}

// Packed f32x2 -> f16x2 (rtz), bit-cast to our _Float16 vector type.
__device__ __forceinline__ half2v pk16(float a, float b) {
  fp16x2 t = __builtin_amdgcn_cvt_pkrtz(a, b);
  return __builtin_bit_cast(half2v, t);
}

// ---------------------------------------------------------------------------
// Prep (fused): blocks 0..2047 convert X fp32->fp16; blocks 2048..3071
// transpose+convert the weights.
// ---------------------------------------------------------------------------
__global__ __launch_bounds__(256) void prep(
    const float* __restrict__ X, const float* __restrict__ Wq,
    const float* __restrict__ Wkv, const float* __restrict__ Wo,
    _Float16* __restrict__ X16, _Float16* __restrict__ WqkvT,
    _Float16* __restrict__ WoT)
{
  __shared__ alignas(16) _Float16 Tt[64 * 68];
  const int bid = blockIdx.x;
  if (bid < 2048) {
    size_t gid = (size_t)bid * 256 + threadIdx.x;
    const float4* src = (const float4*)(X) + gid * 2;
    float4 a = src[0], b = src[1];
    half8v h;
    h[0]=(_Float16)a.x; h[1]=(_Float16)a.y; h[2]=(_Float16)a.z; h[3]=(_Float16)a.w;
    h[4]=(_Float16)b.x; h[5]=(_Float16)b.y; h[6]=(_Float16)b.z; h[7]=(_Float16)b.w;
    *((half8v*)X16 + gid) = h;
    return;
  }
  int b = bid - 2048;
  const float* src; _Float16* dst; int N, tk, tn;
  if (b < 256)      { src = Wq;  dst = WqkvT;                 N = 1024; tk = b & 15;        tn = b >> 4; }
  else if (b < 768) { src = Wkv; dst = WqkvT + (size_t)1024 * 1024; N = 2048; tk = (b - 256) & 15; tn = (b - 256) >> 4; }
  else              { src = Wo;  dst = WoT;                   N = 1024; tk = (b - 768) & 15; tn = (b - 768) >> 4; }

  const int t = threadIdx.x;
  {
    int kg = t >> 4, ng = t & 15;
    const float* sp = src + (size_t)(tk * 64 + kg * 4) * N + tn * 64 + ng * 4;
    float4 r0 = *(const float4*)(sp);
    float4 r1 = *(const float4*)(sp + N);
    float4 r2 = *(const float4*)(sp + 2 * N);
    float4 r3 = *(const float4*)(sp + 3 * N);
    half4v h;
    h[0]=(_Float16)r0.x; h[1]=(_Float16)r1.x; h[2]=(_Float16)r2.x; h[3]=(_Float16)r3.x;
    *(half4v*)&Tt[(ng * 4 + 0) * 68 + kg * 4] = h;
    h[0]=(_Float16)r0.y; h[1]=(_Float16)r1.y; h[2]=(_Float16)r2.y; h[3]=(_Float16)r3.y;
    *(half4v*)&Tt[(ng * 4 + 1) * 68 + kg * 4] = h;
    h[0]=(_Float16)r0.z; h[1]=(_Float16)r1.z; h[2]=(_Float16)r2.z; h[3]=(_Float16)r3.z;
    *(half4v*)&Tt[(ng * 4 + 2) * 68 + kg * 4] = h;
    h[0]=(_Float16)r0.w; h[1]=(_Float16)r1.w; h[2]=(_Float16)r2.w; h[3]=(_Float16)r3.w;
    *(half4v*)&Tt[(ng * 4 + 3) * 68 + kg * 4] = h;
  }
  __syncthreads();
  #pragma unroll
  for (int i = 0; i < 2; i++) {
    int idx = t + i * 256;
    int nl = idx >> 3, k8 = (idx & 7) * 8;
    half8v v = *(half8v*)&Tt[nl * 68 + k8];
    *(half8v*)(dst + (size_t)(tn * 64 + nl) * 1024 + tk * 64 + k8) = v;
  }
}

// ---------------------------------------------------------------------------
// Kernel 1: QKV projection, m97 structure (unchanged from R8).
// ---------------------------------------------------------------------------
__global__ __launch_bounds__(256) void qkv_gemm(
    const _Float16* __restrict__ X16, const _Float16* __restrict__ WqkvT,
    _Float16* __restrict__ q_ws, _Float16* __restrict__ k_ws,
    _Float16* __restrict__ vT_ws)
{
  constexpr int K = 1024;
  __shared__ alignas(16) _Float16 As[128 * 32];
  __shared__ alignas(16) _Float16 Bs[128 * 32];

  const int m0 = blockIdx.x * 128;
  const int n0 = blockIdx.y * 128;

  const int tid  = threadIdx.x;
  const int wave = tid >> 6, lane = tid & 63;
  const int qd = lane >> 4, l15 = lane & 15;
  const int wr = (wave >> 1) * 64, wc = (wave & 1) * 64;
  const int r0i = tid >> 2, c0 = (tid & 3) * 8;

  floatx4 acc[4][4] = {};

  for (int k0 = 0; k0 < K; k0 += 32) {
    gld_lds16(X16 + (size_t)(m0 + r0i) * K + k0 + c0, &As[tid * 8]);
    gld_lds16(X16 + (size_t)(m0 + 64 + r0i) * K + k0 + c0, &As[(tid + 256) * 8]);
    gld_lds16(WqkvT + (size_t)(n0 + r0i) * K + k0 + c0, &Bs[tid * 8]);
    gld_lds16(WqkvT + (size_t)(n0 + 64 + r0i) * K + k0 + c0, &Bs[(tid + 256) * 8]);
    __syncthreads();
    half8v a[4], b[4];
    #pragma unroll
    for (int it = 0; it < 4; it++)
      a[it] = *(half8v*)&As[(wr + it * 16 + l15) * 32 + qd * 8];
    #pragma unroll
    for (int jt = 0; jt < 4; jt++)
      b[jt] = *(half8v*)&Bs[(wc + jt * 16 + l15) * 32 + qd * 8];
    #pragma unroll
    for (int it = 0; it < 4; it++)
      #pragma unroll
      for (int jt = 0; jt < 4; jt++)
        acc[it][jt] = MFMA16(a[it], b[jt], acc[it][jt]);
    __syncthreads();
  }

  #pragma unroll
  for (int it = 0; it < 4; it++) {
    #pragma unroll
    for (int jt = 0; jt < 4; jt++) {
      #pragma unroll
      for (int r = 0; r < 4; r++) {
        int m = m0 + wr + it * 16 + qd * 4 + r;
        int n = n0 + wc + jt * 16 + l15;
        float val = acc[it][jt][r];
        int bb = m >> 11, nn = m & 2047;
        if (n0 < 1024) {
          int h = n >> 6, d = n & 63;
          q_ws[(((size_t)bb * 16 + h) * 2048 + nn) * 64 + d] = (_Float16)(val * QSCALE);
        } else if (n0 < 2048) {
          int c = n - 1024, h = c >> 6, d = c & 63;
          k_ws[(((size_t)bb * 16 + h) * 2048 + nn) * 64 + d] = (_Float16)val;
        } else {
          int c = n - 2048, h = c >> 6, d = c & 63;
          vT_ws[(((size_t)bb * 16 + h) * 64 + d) * 2048 + nn] = (_Float16)val;
        }
      }
    }
  }
}

// ---------------------------------------------------------------------------
// Kernel 2: flash attention v7 — K/V/Q staging via global_load_lds.
// The XOR bank-swizzle is applied on the SOURCE column index (per-lane global
// addresses are free); the LDS dest is the required uniform-base + lane*16.
// LDS contents are bit-identical to R8's layout, so all frag reads keep the
// swz() pattern. Deletes 8 ds_write_b128 + 8 global->VGPR loads per wave-iter
// and frees 32 VGPRs. Double buffer: async loads into buf[p^1] at iter top,
// compute on buf[p], one barrier at iter end (drains vmcnt with full cover).
// ---------------------------------------------------------------------------
__device__ __forceinline__ int swz(int row, int blk) {
  return row * 64 + ((blk ^ (row & 7)) << 3);
}

__global__ __launch_bounds__(128, 2) void attn_kernel(
    const _Float16* __restrict__ q_ws, const _Float16* __restrict__ k_ws,
    const _Float16* __restrict__ vT_ws, _Float16* __restrict__ aout)
{
  constexpr int N = 2048;
  __shared__ alignas(16) _Float16 Qs[64 * 64];      // Q staging -> P buffer
  __shared__ alignas(16) _Float16 Ks[2][64 * 64];   // double-buffered K
  __shared__ alignas(16) _Float16 Vts[2][64 * 64];  // double-buffered V^T

  const int id = blockIdx.x;
  const int bh = ((id >> 8) << 3) | (id & 7);
  const int qt = (id >> 3) & 31;

  const _Float16* Qp = q_ws + (size_t)bh * N * 64;
  const _Float16* Kp = k_ws + (size_t)bh * N * 64;
  const _Float16* Vp = vT_ws + (size_t)bh * 64 * N;

  const int tid = threadIdx.x, wave = tid >> 6, lane = tid & 63;
  const int qd = lane >> 4, l15 = lane & 15;
  const int q0 = qt * 64;
  const int wbase = wave * 32;

  // Prologue: async-stage Q tile and K/V tile 0 (source-side XOR swizzle).
  #pragma unroll
  for (int i = 0; i < 4; i++) {
    int idx = tid + i * 128;
    int r = idx >> 3, cb = (idx ^ r) & 7;
    gld_lds16(Qp + (size_t)(q0 + r) * 64 + cb * 8, &Qs[idx * 8]);
    gld_lds16(Kp + (size_t)r * 64 + cb * 8, &Ks[0][idx * 8]);
    gld_lds16(Vp + (size_t)r * N + cb * 8, &Vts[0][idx * 8]);
  }
  __syncthreads();  // drains vmcnt: Q, K0, V0 resident

  half8v qf[2][2];
  #pragma unroll
  for (int m = 0; m < 2; m++)
    #pragma unroll
    for (int ks = 0; ks < 2; ks++)
      qf[m][ks] = *(half8v*)&Qs[swz(wbase + m * 16 + l15, ks * 4 + qd)];

  floatx4 o[2][4] = {};
  float lsum[2] = {};

  int p = 0;
  for (int kv0 = 0; kv0 < N; kv0 += 64) {
    const bool more = (kv0 + 64) < N;
    // Async prefetch next K/V tile into buf[p^1] — covered by compute below.
    if (more) {
      int kvn = kv0 + 64;
      #pragma unroll
      for (int i = 0; i < 4; i++) {
        int idx = tid + i * 128;
        int r = idx >> 3, cb = (idx ^ r) & 7;
        gld_lds16(Kp + (size_t)(kvn + r) * 64 + cb * 8, &Ks[p ^ 1][idx * 8]);
        gld_lds16(Vp + (size_t)r * N + kvn + cb * 8, &Vts[p ^ 1][idx * 8]);
      }
    }

    // S^T = K·Q^T : s[nt][m] C-layout kv = nt*16+qd*4+r, q = m*16+l15.
    floatx4 s[4][2] = {};
    #pragma unroll
    for (int ks = 0; ks < 2; ks++) {
      half8v kf[4];
      #pragma unroll
      for (int nt = 0; nt < 4; nt++)
        kf[nt] = *(half8v*)&Ks[p][swz(nt * 16 + l15, ks * 4 + qd)];
      #pragma unroll
      for (int nt = 0; nt < 4; nt++)
        #pragma unroll
        for (int m = 0; m < 2; m++)
          s[nt][m] = MFMA16(kf[nt], qf[m][ks], s[nt][m]);
    }

    // p = 2^s; per-lane partial row sums (q = l15); pack half4 and write to
    // P buffer (wave-private rows of Qs) as kv-contiguous b64.
    #pragma unroll
    for (int m = 0; m < 2; m++) {
      #pragma unroll
      for (int nt = 0; nt < 4; nt++) {
        float p0 = __builtin_amdgcn_exp2f(s[nt][m][0]);
        float p1 = __builtin_amdgcn_exp2f(s[nt][m][1]);
        float p2 = __builtin_amdgcn_exp2f(s[nt][m][2]);
        float p3 = __builtin_amdgcn_exp2f(s[nt][m][3]);
        lsum[m] += (p0 + p1) + (p2 + p3);
        half2v h01 = pk16(p0, p1);
        half2v h23 = pk16(p2, p3);
        half4v pk;
        pk[0] = h01[0]; pk[1] = h01[1]; pk[2] = h23[0]; pk[3] = h23[1];
        *(half4v*)&Qs[swz(wbase + m * 16 + l15, 2 * nt + (qd >> 1)) +
                      (qd & 1) * 4] = pk;
      }
    }

    // O += P·V, full-rate K=32 MFMA.
    #pragma unroll
    for (int ks = 0; ks < 2; ks++) {
      half8v pf[2], vf[4];
      #pragma unroll
      for (int m = 0; m < 2; m++)
        pf[m] = *(half8v*)&Qs[swz(wbase + m * 16 + l15, 4 * ks + qd)];
      #pragma unroll
      for (int nt = 0; nt < 4; nt++)
        vf[nt] = *(half8v*)&Vts[p][swz(nt * 16 + l15, 4 * ks + qd)];
      #pragma unroll
      for (int m = 0; m < 2; m++)
        #pragma unroll
        for (int nt = 0; nt < 4; nt++)
          o[m][nt] = MFMA16(pf[m], vf[nt], o[m][nt]);
    }

    // End-of-iter barrier: separates this iter's reads of buf[p] from the
    // next iter's async writes into it, and drains vmcnt so buf[p^1] is
    // complete before it's read.
    if (more) __syncthreads();
    p ^= 1;
  }

  // lsum per q=l15, partial over quads: reduce, redistribute via shfl.
  #pragma unroll
  for (int m = 0; m < 2; m++) {
    lsum[m] += __shfl_xor(lsum[m], 16);
    lsum[m] += __shfl_xor(lsum[m], 32);
  }

  const int bb = bh >> 4, hh = bh & 15;
  #pragma unroll
  for (int m = 0; m < 2; m++) {
    #pragma unroll
    for (int r = 0; r < 4; r++) {
      float inv = 1.0f / __shfl(lsum[m], qd * 4 + r);
      int n = q0 + wbase + m * 16 + qd * 4 + r;
      #pragma unroll
      for (int dt = 0; dt < 4; dt++) {
        int d = dt * 16 + l15;
        aout[((size_t)(bb * 2048 + n)) * 1024 + hh * 64 + d] =
            (_Float16)(o[m][dt][r] * inv);
      }
    }
  }
}

// ---------------------------------------------------------------------------
// Kernel 3: out projection, m97 structure (unchanged from R8).
// ---------------------------------------------------------------------------
__global__ __launch_bounds__(256) void out_gemm(
    const _Float16* __restrict__ A, const _Float16* __restrict__ WoT,
    const float* __restrict__ bo, float* __restrict__ Out)
{
  constexpr int K = 1024;
  __shared__ alignas(16) _Float16 As[128 * 32];
  __shared__ alignas(16) _Float16 Bs[128 * 32];

  const int m0 = blockIdx.x * 128;
  const int n0 = blockIdx.y * 128;
  const int tid = threadIdx.x;
  const int wave = tid >> 6, lane = tid & 63;
  const int qd = lane >> 4, l15 = lane & 15;
  const int wr = (wave >> 1) * 64, wc = (wave & 1) * 64;
  const int r0i = tid >> 2, c0 = (tid & 3) * 8;

  floatx4 acc[4][4] = {};

  for (int k0 = 0; k0 < K; k0 += 32) {
    gld_lds16(A + (size_t)(m0 + r0i) * K + k0 + c0, &As[tid * 8]);
    gld_lds16(A + (size_t)(m0 + 64 + r0i) * K + k0 + c0, &As[(tid + 256) * 8]);
    gld_lds16(WoT + (size_t)(n0 + r0i) * K + k0 + c0, &Bs[tid * 8]);
    gld_lds16(WoT + (size_t)(n0 + 64 + r0i) * K + k0 + c0, &Bs[(tid + 256) * 8]);
    __syncthreads();
    half8v a[4], b[4];
    #pragma unroll
    for (int it = 0; it < 4; it++)
      a[it] = *(half8v*)&As[(wr + it * 16 + l15) * 32 + qd * 8];
    #pragma unroll
    for (int jt = 0; jt < 4; jt++)
      b[jt] = *(half8v*)&Bs[(wc + jt * 16 + l15) * 32 + qd * 8];
    #pragma unroll
    for (int it = 0; it < 4; it++)
      #pragma unroll
      for (int jt = 0; jt < 4; jt++)
        acc[it][jt] = MFMA16(a[it], b[jt], acc[it][jt]);
    __syncthreads();
  }

  #pragma unroll
  for (int it = 0; it < 4; it++) {
    #pragma unroll
    for (int jt = 0; jt < 4; jt++) {
      int n = n0 + wc + jt * 16 + l15;
      float bias = bo[n];
      #pragma unroll
      for (int r = 0; r < 4; r++) {
        int m = m0 + wr + it * 16 + qd * 4 + r;
        Out[(size_t)m * 1024 + n] = acc[it][jt][r] + bias;
      }
    }
  }
}

// ---------------------------------------------------------------------------
extern "C" void kernel_launch(void* const* d_in, const int* in_sizes, int n_in,
                              void* d_out, int out_size, void* d_ws, size_t ws_size,
                              hipStream_t stream) {
  const float* X   = (const float*)d_in[0];
  const float* Wq  = (const float*)d_in[1];
  const float* Wkv = (const float*)d_in[2];
  const float* Wo  = (const float*)d_in[3];
  const float* bo  = (const float*)d_in[4];
  float* out = (float*)d_out;

  const size_t M4 = (size_t)4 * 1024 * 1024;
  _Float16* q_ws   = (_Float16*)d_ws;
  _Float16* k_ws   = q_ws + M4;
  _Float16* vT_ws  = k_ws + M4;
  _Float16* X16    = vT_ws + M4;
  _Float16* WqkvT  = X16 + M4;
  _Float16* WoT    = WqkvT + (size_t)3 * 1024 * 1024;
  _Float16* aout   = X16;  // X16 dead after qkv_gemm

  prep<<<3072, 256, 0, stream>>>(X, Wq, Wkv, Wo, X16, WqkvT, WoT);
  qkv_gemm<<<dim3(32, 24), 256, 0, stream>>>(X16, WqkvT, q_ws, k_ws, vT_ws);
  attn_kernel<<<1024, 128, 0, stream>>>(q_ws, k_ws, vT_ws, aout);
  out_gemm<<<dim3(32, 8), 256, 0, stream>>>(aout, WoT, bo, out);
}

// Round 10
// 190.315 us; speedup vs baseline: 1.0279x; 1.0279x over previous
//
#include <hip/hip_runtime.h>
#include <math.h>
#include <stdint.h>

typedef _Float16 half8v __attribute__((ext_vector_type(8)));
typedef _Float16 half4v __attribute__((ext_vector_type(4)));
typedef _Float16 half2v __attribute__((ext_vector_type(2)));
typedef __fp16 fp16x2 __attribute__((ext_vector_type(2)));
typedef float floatx4 __attribute__((ext_vector_type(4)));

#define MFMA16(a, b, c) __builtin_amdgcn_mfma_f32_16x16x32_f16(a, b, c, 0, 0, 0)

// Q pre-scale: 1/sqrt(64) * log2(e), folded so attention uses exp2 directly.
#define QSCALE 0.18033688011112f

// Async global->LDS, 16B per lane. LDS dest must be wave-uniform base + lane*16;
// the GLOBAL source address is per-lane arbitrary (it's a gather).
__device__ __forceinline__ void gld_lds16(const void* g, void* l) {
  __builtin_amdgcn_global_load_lds(
      (const __attribute__((address_space(1))) uint32_t*)(uintptr_t)g,
      (__attribute__((address_space(3))) uint32_t*)(uintptr_t)l, 16, 0, 0);
}

// Packed f32x2 -> f16x2 (rtz), bit-cast to our _Float16 vector type.
__device__ __forceinline__ half2v pk16(float a, float b) {
  fp16x2 t = __builtin_amdgcn_cvt_pkrtz(a, b);
  return __builtin_bit_cast(half2v, t);
}

// ---------------------------------------------------------------------------
// Prep (fused): blocks 0..2047 convert X fp32->fp16; blocks 2048..3071
// transpose+convert the weights.
// ---------------------------------------------------------------------------
__global__ __launch_bounds__(256) void prep(
    const float* __restrict__ X, const float* __restrict__ Wq,
    const float* __restrict__ Wkv, const float* __restrict__ Wo,
    _Float16* __restrict__ X16, _Float16* __restrict__ WqkvT,
    _Float16* __restrict__ WoT)
{
  __shared__ alignas(16) _Float16 Tt[64 * 68];
  const int bid = blockIdx.x;
  if (bid < 2048) {
    size_t gid = (size_t)bid * 256 + threadIdx.x;
    const float4* src = (const float4*)(X) + gid * 2;
    float4 a = src[0], b = src[1];
    half8v h;
    h[0]=(_Float16)a.x; h[1]=(_Float16)a.y; h[2]=(_Float16)a.z; h[3]=(_Float16)a.w;
    h[4]=(_Float16)b.x; h[5]=(_Float16)b.y; h[6]=(_Float16)b.z; h[7]=(_Float16)b.w;
    *((half8v*)X16 + gid) = h;
    return;
  }
  int b = bid - 2048;
  const float* src; _Float16* dst; int N, tk, tn;
  if (b < 256)      { src = Wq;  dst = WqkvT;                 N = 1024; tk = b & 15;        tn = b >> 4; }
  else if (b < 768) { src = Wkv; dst = WqkvT + (size_t)1024 * 1024; N = 2048; tk = (b - 256) & 15; tn = (b - 256) >> 4; }
  else              { src = Wo;  dst = WoT;                   N = 1024; tk = (b - 768) & 15; tn = (b - 768) >> 4; }

  const int t = threadIdx.x;
  {
    int kg = t >> 4, ng = t & 15;
    const float* sp = src + (size_t)(tk * 64 + kg * 4) * N + tn * 64 + ng * 4;
    float4 r0 = *(const float4*)(sp);
    float4 r1 = *(const float4*)(sp + N);
    float4 r2 = *(const float4*)(sp + 2 * N);
    float4 r3 = *(const float4*)(sp + 3 * N);
    half4v h;
    h[0]=(_Float16)r0.x; h[1]=(_Float16)r1.x; h[2]=(_Float16)r2.x; h[3]=(_Float16)r3.x;
    *(half4v*)&Tt[(ng * 4 + 0) * 68 + kg * 4] = h;
    h[0]=(_Float16)r0.y; h[1]=(_Float16)r1.y; h[2]=(_Float16)r2.y; h[3]=(_Float16)r3.y;
    *(half4v*)&Tt[(ng * 4 + 1) * 68 + kg * 4] = h;
    h[0]=(_Float16)r0.z; h[1]=(_Float16)r1.z; h[2]=(_Float16)r2.z; h[3]=(_Float16)r3.z;
    *(half4v*)&Tt[(ng * 4 + 2) * 68 + kg * 4] = h;
    h[0]=(_Float16)r0.w; h[1]=(_Float16)r1.w; h[2]=(_Float16)r2.w; h[3]=(_Float16)r3.w;
    *(half4v*)&Tt[(ng * 4 + 3) * 68 + kg * 4] = h;
  }
  __syncthreads();
  #pragma unroll
  for (int i = 0; i < 2; i++) {
    int idx = t + i * 256;
    int nl = idx >> 3, k8 = (idx & 7) * 8;
    half8v v = *(half8v*)&Tt[nl * 68 + k8];
    *(half8v*)(dst + (size_t)(tn * 64 + nl) * 1024 + tk * 64 + k8) = v;
  }
}

// ---------------------------------------------------------------------------
// Kernel 1: QKV projection, m97 structure. vT epilogue (n0>=2048) now goes
// through an LDS transpose (reusing the As/Bs memory, dead after the K-loop)
// and stores coalesced half8 rows instead of 16-lane x 4KB-strided scalar
// half stores.
// ---------------------------------------------------------------------------
__global__ __launch_bounds__(256) void qkv_gemm(
    const _Float16* __restrict__ X16, const _Float16* __restrict__ WqkvT,
    _Float16* __restrict__ q_ws, _Float16* __restrict__ k_ws,
    _Float16* __restrict__ vT_ws)
{
  constexpr int K = 1024;
  // 128*136 halves = 34816 B. During the K-loop: As = Tt[0..4095],
  // Bs = Tt[4096..8191]. After the loop (vT blocks) the whole buffer is a
  // 128x136 fp16 transpose scratch (stride 136 halves = 272 B, 16B aligned).
  __shared__ alignas(16) _Float16 Tt[128 * 136];
  _Float16* As = Tt;
  _Float16* Bs = Tt + 4096;

  const int m0 = blockIdx.x * 128;
  const int n0 = blockIdx.y * 128;

  const int tid  = threadIdx.x;
  const int wave = tid >> 6, lane = tid & 63;
  const int qd = lane >> 4, l15 = lane & 15;
  const int wr = (wave >> 1) * 64, wc = (wave & 1) * 64;
  const int r0i = tid >> 2, c0 = (tid & 3) * 8;

  floatx4 acc[4][4] = {};

  for (int k0 = 0; k0 < K; k0 += 32) {
    gld_lds16(X16 + (size_t)(m0 + r0i) * K + k0 + c0, &As[tid * 8]);
    gld_lds16(X16 + (size_t)(m0 + 64 + r0i) * K + k0 + c0, &As[(tid + 256) * 8]);
    gld_lds16(WqkvT + (size_t)(n0 + r0i) * K + k0 + c0, &Bs[tid * 8]);
    gld_lds16(WqkvT + (size_t)(n0 + 64 + r0i) * K + k0 + c0, &Bs[(tid + 256) * 8]);
    __syncthreads();
    half8v a[4], b[4];
    #pragma unroll
    for (int it = 0; it < 4; it++)
      a[it] = *(half8v*)&As[(wr + it * 16 + l15) * 32 + qd * 8];
    #pragma unroll
    for (int jt = 0; jt < 4; jt++)
      b[jt] = *(half8v*)&Bs[(wc + jt * 16 + l15) * 32 + qd * 8];
    #pragma unroll
    for (int it = 0; it < 4; it++)
      #pragma unroll
      for (int jt = 0; jt < 4; jt++)
        acc[it][jt] = MFMA16(a[it], b[jt], acc[it][jt]);
    __syncthreads();
  }

  if (n0 < 2048) {
    // q/k epilogue: d = l15 contiguous -> 32B per quad, acceptable.
    #pragma unroll
    for (int it = 0; it < 4; it++) {
      #pragma unroll
      for (int jt = 0; jt < 4; jt++) {
        #pragma unroll
        for (int r = 0; r < 4; r++) {
          int m = m0 + wr + it * 16 + qd * 4 + r;
          int n = n0 + wc + jt * 16 + l15;
          float val = acc[it][jt][r];
          int bb = m >> 11, nn = m & 2047;
          if (n0 < 1024) {
            int h = n >> 6, d = n & 63;
            q_ws[(((size_t)bb * 16 + h) * 2048 + nn) * 64 + d] = (_Float16)(val * QSCALE);
          } else {
            int c = n - 1024, h = c >> 6, d = c & 63;
            k_ws[(((size_t)bb * 16 + h) * 2048 + nn) * 64 + d] = (_Float16)val;
          }
        }
      }
    }
  } else {
    // vT epilogue: transpose in LDS, then coalesced half8 row stores.
    // (Last loop barrier already separates MFMA reads from this reuse.)
    #pragma unroll
    for (int it = 0; it < 4; it++) {
      #pragma unroll
      for (int jt = 0; jt < 4; jt++) {
        #pragma unroll
        for (int r = 0; r < 4; r++) {
          int ml = wr + it * 16 + qd * 4 + r;
          int nl = wc + jt * 16 + l15;
          Tt[nl * 136 + ml] = (_Float16)acc[it][jt][r];
        }
      }
    }
    __syncthreads();
    int row = tid >> 1;              // n-local 0..127
    int mh  = (tid & 1) * 64;        // m-half
    int c   = (n0 - 2048) + row;     // 0..1023
    int bb  = m0 >> 11;
    int nnb = (m0 & 2047) + mh;
    _Float16* dstp =
        vT_ws + (((size_t)bb * 16 + (c >> 6)) * 64 + (c & 63)) * 2048 + nnb;
    #pragma unroll
    for (int i = 0; i < 8; i++)
      *(half8v*)(dstp + i * 8) = *(half8v*)&Tt[row * 136 + mh + i * 8];
  }
}

// ---------------------------------------------------------------------------
// Kernel 2: flash attention v7 (unchanged from R9).
// ---------------------------------------------------------------------------
__device__ __forceinline__ int swz(int row, int blk) {
  return row * 64 + ((blk ^ (row & 7)) << 3);
}

__global__ __launch_bounds__(128, 2) void attn_kernel(
    const _Float16* __restrict__ q_ws, const _Float16* __restrict__ k_ws,
    const _Float16* __restrict__ vT_ws, _Float16* __restrict__ aout)
{
  constexpr int N = 2048;
  __shared__ alignas(16) _Float16 Qs[64 * 64];      // Q staging -> P buffer
  __shared__ alignas(16) _Float16 Ks[2][64 * 64];   // double-buffered K
  __shared__ alignas(16) _Float16 Vts[2][64 * 64];  // double-buffered V^T

  const int id = blockIdx.x;
  const int bh = ((id >> 8) << 3) | (id & 7);
  const int qt = (id >> 3) & 31;

  const _Float16* Qp = q_ws + (size_t)bh * N * 64;
  const _Float16* Kp = k_ws + (size_t)bh * N * 64;
  const _Float16* Vp = vT_ws + (size_t)bh * 64 * N;

  const int tid = threadIdx.x, wave = tid >> 6, lane = tid & 63;
  const int qd = lane >> 4, l15 = lane & 15;
  const int q0 = qt * 64;
  const int wbase = wave * 32;

  // Prologue: async-stage Q tile and K/V tile 0 (source-side XOR swizzle).
  #pragma unroll
  for (int i = 0; i < 4; i++) {
    int idx = tid + i * 128;
    int r = idx >> 3, cb = (idx ^ r) & 7;
    gld_lds16(Qp + (size_t)(q0 + r) * 64 + cb * 8, &Qs[idx * 8]);
    gld_lds16(Kp + (size_t)r * 64 + cb * 8, &Ks[0][idx * 8]);
    gld_lds16(Vp + (size_t)r * N + cb * 8, &Vts[0][idx * 8]);
  }
  __syncthreads();  // drains vmcnt: Q, K0, V0 resident

  half8v qf[2][2];
  #pragma unroll
  for (int m = 0; m < 2; m++)
    #pragma unroll
    for (int ks = 0; ks < 2; ks++)
      qf[m][ks] = *(half8v*)&Qs[swz(wbase + m * 16 + l15, ks * 4 + qd)];

  floatx4 o[2][4] = {};
  float lsum[2] = {};

  int p = 0;
  for (int kv0 = 0; kv0 < N; kv0 += 64) {
    const bool more = (kv0 + 64) < N;
    // Async prefetch next K/V tile into buf[p^1] — covered by compute below.
    if (more) {
      int kvn = kv0 + 64;
      #pragma unroll
      for (int i = 0; i < 4; i++) {
        int idx = tid + i * 128;
        int r = idx >> 3, cb = (idx ^ r) & 7;
        gld_lds16(Kp + (size_t)(kvn + r) * 64 + cb * 8, &Ks[p ^ 1][idx * 8]);
        gld_lds16(Vp + (size_t)r * N + kvn + cb * 8, &Vts[p ^ 1][idx * 8]);
      }
    }

    // S^T = K·Q^T : s[nt][m] C-layout kv = nt*16+qd*4+r, q = m*16+l15.
    floatx4 s[4][2] = {};
    #pragma unroll
    for (int ks = 0; ks < 2; ks++) {
      half8v kf[4];
      #pragma unroll
      for (int nt = 0; nt < 4; nt++)
        kf[nt] = *(half8v*)&Ks[p][swz(nt * 16 + l15, ks * 4 + qd)];
      #pragma unroll
      for (int nt = 0; nt < 4; nt++)
        #pragma unroll
        for (int m = 0; m < 2; m++)
          s[nt][m] = MFMA16(kf[nt], qf[m][ks], s[nt][m]);
    }

    // p = 2^s; per-lane partial row sums (q = l15); pack half4 and write to
    // P buffer (wave-private rows of Qs) as kv-contiguous b64.
    #pragma unroll
    for (int m = 0; m < 2; m++) {
      #pragma unroll
      for (int nt = 0; nt < 4; nt++) {
        float p0 = __builtin_amdgcn_exp2f(s[nt][m][0]);
        float p1 = __builtin_amdgcn_exp2f(s[nt][m][1]);
        float p2 = __builtin_amdgcn_exp2f(s[nt][m][2]);
        float p3 = __builtin_amdgcn_exp2f(s[nt][m][3]);
        lsum[m] += (p0 + p1) + (p2 + p3);
        half2v h01 = pk16(p0, p1);
        half2v h23 = pk16(p2, p3);
        half4v pk;
        pk[0] = h01[0]; pk[1] = h01[1]; pk[2] = h23[0]; pk[3] = h23[1];
        *(half4v*)&Qs[swz(wbase + m * 16 + l15, 2 * nt + (qd >> 1)) +
                      (qd & 1) * 4] = pk;
      }
    }

    // O += P·V, full-rate K=32 MFMA.
    #pragma unroll
    for (int ks = 0; ks < 2; ks++) {
      half8v pf[2], vf[4];
      #pragma unroll
      for (int m = 0; m < 2; m++)
        pf[m] = *(half8v*)&Qs[swz(wbase + m * 16 + l15, 4 * ks + qd)];
      #pragma unroll
      for (int nt = 0; nt < 4; nt++)
        vf[nt] = *(half8v*)&Vts[p][swz(nt * 16 + l15, 4 * ks + qd)];
      #pragma unroll
      for (int m = 0; m < 2; m++)
        #pragma unroll
        for (int nt = 0; nt < 4; nt++)
          o[m][nt] = MFMA16(pf[m], vf[nt], o[m][nt]);
    }

    // End-of-iter barrier: separates this iter's reads of buf[p] from the
    // next iter's async writes into it, and drains vmcnt so buf[p^1] is
    // complete before it's read.
    if (more) __syncthreads();
    p ^= 1;
  }

  // lsum per q=l15, partial over quads: reduce, redistribute via shfl.
  #pragma unroll
  for (int m = 0; m < 2; m++) {
    lsum[m] += __shfl_xor(lsum[m], 16);
    lsum[m] += __shfl_xor(lsum[m], 32);
  }

  const int bb = bh >> 4, hh = bh & 15;
  #pragma unroll
  for (int m = 0; m < 2; m++) {
    #pragma unroll
    for (int r = 0; r < 4; r++) {
      float inv = 1.0f / __shfl(lsum[m], qd * 4 + r);
      int n = q0 + wbase + m * 16 + qd * 4 + r;
      #pragma unroll
      for (int dt = 0; dt < 4; dt++) {
        int d = dt * 16 + l15;
        aout[((size_t)(bb * 2048 + n)) * 1024 + hh * 64 + d] =
            (_Float16)(o[m][dt][r] * inv);
      }
    }
  }
}

// ---------------------------------------------------------------------------
// Kernel 3: out projection. 64(M)x128(N) tiles -> grid (64,8) = 512 blocks
// = 2 blocks/CU so barrier stalls overlap across blocks (was 1 block/CU).
// ---------------------------------------------------------------------------
__global__ __launch_bounds__(256) void out_gemm(
    const _Float16* __restrict__ A, const _Float16* __restrict__ WoT,
    const float* __restrict__ bo, float* __restrict__ Out)
{
  constexpr int K = 1024;
  __shared__ alignas(16) _Float16 As[64 * 32];
  __shared__ alignas(16) _Float16 Bs[128 * 32];

  const int m0 = blockIdx.x * 64;
  const int n0 = blockIdx.y * 128;
  const int tid = threadIdx.x;
  const int wave = tid >> 6, lane = tid & 63;
  const int qd = lane >> 4, l15 = lane & 15;
  const int wr = (wave >> 1) * 32, wc = (wave & 1) * 64;
  const int r0i = tid >> 2, c0 = (tid & 3) * 8;

  floatx4 acc[2][4] = {};

  for (int k0 = 0; k0 < K; k0 += 32) {
    gld_lds16(A + (size_t)(m0 + r0i) * K + k0 + c0, &As[tid * 8]);
    gld_lds16(WoT + (size_t)(n0 + r0i) * K + k0 + c0, &Bs[tid * 8]);
    gld_lds16(WoT + (size_t)(n0 + 64 + r0i) * K + k0 + c0, &Bs[(tid + 256) * 8]);
    __syncthreads();
    half8v a[2], b[4];
    #pragma unroll
    for (int it = 0; it < 2; it++)
      a[it] = *(half8v*)&As[(wr + it * 16 + l15) * 32 + qd * 8];
    #pragma unroll
    for (int jt = 0; jt < 4; jt++)
      b[jt] = *(half8v*)&Bs[(wc + jt * 16 + l15) * 32 + qd * 8];
    #pragma unroll
    for (int it = 0; it < 2; it++)
      #pragma unroll
      for (int jt = 0; jt < 4; jt++)
        acc[it][jt] = MFMA16(a[it], b[jt], acc[it][jt]);
    __syncthreads();
  }

  #pragma unroll
  for (int it = 0; it < 2; it++) {
    #pragma unroll
    for (int jt = 0; jt < 4; jt++) {
      int n = n0 + wc + jt * 16 + l15;
      float bias = bo[n];
      #pragma unroll
      for (int r = 0; r < 4; r++) {
        int m = m0 + wr + it * 16 + qd * 4 + r;
        Out[(size_t)m * 1024 + n] = acc[it][jt][r] + bias;
      }
    }
  }
}

// ---------------------------------------------------------------------------
extern "C" void kernel_launch(void* const* d_in, const int* in_sizes, int n_in,
                              void* d_out, int out_size, void* d_ws, size_t ws_size,
                              hipStream_t stream) {
  const float* X   = (const float*)d_in[0];
  const float* Wq  = (const float*)d_in[1];
  const float* Wkv = (const float*)d_in[2];
  const float* Wo  = (const float*)d_in[3];
  const float* bo  = (const float*)d_in[4];
  float* out = (float*)d_out;

  const size_t M4 = (size_t)4 * 1024 * 1024;
  _Float16* q_ws   = (_Float16*)d_ws;
  _Float16* k_ws   = q_ws + M4;
  _Float16* vT_ws  = k_ws + M4;
  _Float16* X16    = vT_ws + M4;
  _Float16* WqkvT  = X16 + M4;
  _Float16* WoT    = WqkvT + (size_t)3 * 1024 * 1024;
  _Float16* aout   = X16;  // X16 dead after qkv_gemm

  prep<<<3072, 256, 0, stream>>>(X, Wq, Wkv, Wo, X16, WqkvT, WoT);
  qkv_gemm<<<dim3(32, 24), 256, 0, stream>>>(X16, WqkvT, q_ws, k_ws, vT_ws);
  attn_kernel<<<1024, 128, 0, stream>>>(q_ws, k_ws, vT_ws, aout);
  out_gemm<<<dim3(64, 8), 256, 0, stream>>>(aout, WoT, bo, out);
}